// Round 1
// baseline (2640.876 us; speedup 1.0000x reference)
//
#include <hip/hip_runtime.h>
#include <math.h>

// ---------------- problem constants ----------------
#define BB 2
#define D_ 384
#define H_ 12
#define HD 32
#define NIN 4096            // 64*64
#define NOUT 484            // 22*22
#define MOUT (BB*NOUT)      // 968
#define MIN_ (BB*NIN)       // 8192
#define QW_ 22
#define CK 18816            // D*7*7
#define KSPLIT 12
#define KSEG (CK/KSPLIT)    // 1568
#define LN_EPS 1e-5f
#define EPS_ 1.1920929e-07f

// ---------------- ws layout (floats) ----------------
// all offsets multiples of 4 floats (16B aligned)
static const size_t OXOUT  = 0;                    // 968*384      = 371712
static const size_t OKROSE = 371712;               // 24*4096*32   = 3145728
static const size_t OVH    = OKROSE + 3145728;     // 3145728
static const size_t OQROSE = OVH + 3145728;        // 371712
static const size_t OQP    = OQROSE + 371712;      // 371712
static const size_t OL0    = OQP + 371712;         // 24*512       = 12288
static const size_t OCS    = OL0 + 12288;          // 24*4096      = 98304
static const size_t OUPD   = OCS + 98304;          // 371712
static const size_t OH1    = OUPD + 371712;        // 968*1536     = 1486848
static const size_t OH2    = OH1 + 1486848;        // 371712
// total = 9,747,456 floats = 39 MB

// ---------------- generic 64x64 tiled GEMM: C = A[M,K]*W[K,N] + bias ----------
// ACT: 0 = none, 1 = exact gelu
template<int ACT>
__global__ __launch_bounds__(256)
void gemm64(const float* __restrict__ A, const float* __restrict__ W,
            const float* __restrict__ bias, float* __restrict__ C,
            int M, int N, int K){
  __shared__ float As[16][68];
  __shared__ float Ws[16][68];
  const int t = threadIdx.x;
  const int m0 = blockIdx.x*64, n0 = blockIdx.y*64;
  const int lm = t>>2, lk = (t&3)<<2;     // A loader
  const int wn = (t&15)<<2, wk = t>>4;    // W loader
  const int tm = (t&15)<<2, tn = (t>>4)<<2;
  float acc[4][4];
#pragma unroll
  for (int i=0;i<4;i++)
#pragma unroll
    for (int j=0;j<4;j++) acc[i][j]=0.f;
  for (int kc=0; kc<K; kc+=16){
    float4 av = make_float4(0.f,0.f,0.f,0.f);
    if (m0+lm < M) av = *(const float4*)(A + (size_t)(m0+lm)*K + kc + lk);
    float4 wv = *(const float4*)(W + (size_t)(kc+wk)*N + n0 + wn);
    As[lk+0][lm]=av.x; As[lk+1][lm]=av.y; As[lk+2][lm]=av.z; As[lk+3][lm]=av.w;
    *(float4*)&Ws[wk][wn] = wv;
    __syncthreads();
#pragma unroll
    for (int kk=0;kk<16;kk++){
      float4 a = *(const float4*)&As[kk][tm];
      float4 b = *(const float4*)&Ws[kk][tn];
      float aa[4]={a.x,a.y,a.z,a.w};
      float bb2[4]={b.x,b.y,b.z,b.w};
#pragma unroll
      for (int i=0;i<4;i++)
#pragma unroll
        for (int j=0;j<4;j++) acc[i][j] += aa[i]*bb2[j];
    }
    __syncthreads();
  }
#pragma unroll
  for (int i=0;i<4;i++){
    int m = m0+tm+i;
    if (m < M){
#pragma unroll
      for (int j=0;j<4;j++){
        int n = n0+tn+j;
        float v = acc[i][j] + bias[n];
        if (ACT==1) v = 0.5f*v*(1.f + erff(v*0.7071067811865475f));
        C[(size_t)m*N + n] = v;
      }
    }
  }
}

// ------------- conv_w transpose: Wt[(ky*7+kx)*384+di][n] = cw[n][di][ky][kx] --
__global__ __launch_bounds__(256)
void wtk(const float* __restrict__ cw, float* __restrict__ Wt){
  int i = blockIdx.x*256 + threadIdx.x;
  if (i >= CK*D_) return;
  int n = i / CK;
  int r = i - n*CK;          // r = di*49 + kyx
  int di = r/49, kyx = r - di*49;
  Wt[(size_t)(kyx*D_ + di)*D_ + n] = cw[i];   // coalesced read, scattered write (L2 merges)
}

// -------- implicit-GEMM conv, 128x128 tile, 8x8 micro, split-K=12 -----------
__global__ __launch_bounds__(256)
void convk(const float* __restrict__ x, const float* __restrict__ Wt,
           float* __restrict__ part){
  __shared__ float As[16][132];
  __shared__ float Ws[16][132];
  const int t = threadIdx.x;
  const int m0 = blockIdx.x*128, n0 = blockIdx.y*128, z = blockIdx.z;
  const int lm = t>>1, lh = (t&1)<<3;
  const int wn = (t&31)<<2, wk = t>>5;
  const int tm = (t&15)<<3, tn = (t>>4)<<3;
  const int mg = m0 + lm;
  const int bq = (mg < MOUT) ? mg : 0;
  const int bb = bq/NOUT; const int qq = bq - bb*NOUT;
  const int oy = qq/QW_;   const int ox = qq - oy*QW_;
  float acc[8][8];
#pragma unroll
  for (int i=0;i<8;i++)
#pragma unroll
    for (int j=0;j<8;j++) acc[i][j]=0.f;
  const int kbeg = z*KSEG;
  for (int kc=kbeg; kc<kbeg+KSEG; kc+=16){
    const int kyx = kc/D_;
    const int di0 = kc - kyx*D_;
    const int ky = kyx/7, kx = kyx - ky*7;
    const int iy = oy*3-3+ky, ix = ox*3-3+kx;
    float4 a0 = make_float4(0.f,0.f,0.f,0.f), a1 = a0;
    if (mg < MOUT && iy>=0 && iy<64 && ix>=0 && ix<64){
      const float* p = x + ((size_t)bb*NIN + iy*64 + ix)*D_ + di0 + lh;
      a0 = *(const float4*)p; a1 = *(const float4*)(p+4);
    }
    As[lh+0][lm]=a0.x; As[lh+1][lm]=a0.y; As[lh+2][lm]=a0.z; As[lh+3][lm]=a0.w;
    As[lh+4][lm]=a1.x; As[lh+5][lm]=a1.y; As[lh+6][lm]=a1.z; As[lh+7][lm]=a1.w;
    *(float4*)&Ws[wk][wn]   = *(const float4*)(Wt + (size_t)(kc+wk)*D_   + n0 + wn);
    *(float4*)&Ws[wk+8][wn] = *(const float4*)(Wt + (size_t)(kc+wk+8)*D_ + n0 + wn);
    __syncthreads();
#pragma unroll
    for (int kk=0;kk<16;kk++){
      float4 xa = *(const float4*)&As[kk][tm];
      float4 xb = *(const float4*)&As[kk][tm+4];
      float4 ya = *(const float4*)&Ws[kk][tn];
      float4 yb = *(const float4*)&Ws[kk][tn+4];
      float aa[8]={xa.x,xa.y,xa.z,xa.w,xb.x,xb.y,xb.z,xb.w};
      float bb2[8]={ya.x,ya.y,ya.z,ya.w,yb.x,yb.y,yb.z,yb.w};
#pragma unroll
      for (int i=0;i<8;i++)
#pragma unroll
        for (int j=0;j<8;j++) acc[i][j] += aa[i]*bb2[j];
    }
    __syncthreads();
  }
#pragma unroll
  for (int i=0;i<8;i++){
    int m = m0+tm+i;
    if (m < MOUT){
      float* dst = part + ((size_t)z*MOUT + m)*D_ + n0 + tn;
      *(float4*)dst     = make_float4(acc[i][0],acc[i][1],acc[i][2],acc[i][3]);
      *(float4*)(dst+4) = make_float4(acc[i][4],acc[i][5],acc[i][6],acc[i][7]);
    }
  }
}

// ---------------- block reduction over 384 threads --------------------------
__device__ __forceinline__ float block_sum_384(float v){
  __shared__ float red[6];
#pragma unroll
  for (int o=32;o>0;o>>=1) v += __shfl_down(v,o);
  const int lane = threadIdx.x & 63, w = threadIdx.x >> 6;
  __syncthreads();                 // protect red across repeated calls
  if (lane==0) red[w] = v;
  __syncthreads();
  return red[0]+red[1]+red[2]+red[3]+red[4]+red[5];
}

// LN kernel. MODE 0: in = 12 conv partials (+conv bias) -> write xout
//            MODE 1: in = upd[bh][q][hd] gathered -> xout += LN
//            MODE 2: in = h2[m][d] -> xout += LN
template<int MODE>
__global__ __launch_bounds__(384)
void lnk(const float* __restrict__ in, const float* __restrict__ cb,
         const float* __restrict__ gg, const float* __restrict__ bb,
         float* __restrict__ xout){
  const int m = blockIdx.x, d = threadIdx.x;
  float v;
  if (MODE==0){
    v = cb[d];
#pragma unroll
    for (int z=0; z<KSPLIT; z++) v += in[((size_t)z*MOUT + m)*D_ + d];
  } else if (MODE==1){
    int b = m/NOUT, q = m - b*NOUT;
    int h = d>>5, dd2 = d&31;
    v = in[(((size_t)(b*H_ + h))*NOUT + q)*HD + dd2];
  } else {
    v = in[(size_t)m*D_ + d];
  }
  float mu  = block_sum_384(v) * (1.f/D_);
  float ce  = v - mu;
  float var = block_sum_384(ce*ce) * (1.f/D_);
  float o = ce * rsqrtf(var + LN_EPS) * gg[d] + bb[d];
  float* dst = xout + (size_t)m*D_ + d;
  if (MODE==0) *dst = o;
  else *dst += o;
}

// ------------- rose for K (+ temp scale) and V gather -----------------------
__global__ __launch_bounds__(256)
void rosek(const float* __restrict__ kvbuf, const float* __restrict__ rf,
           const float* __restrict__ temp,
           float* __restrict__ krose, float* __restrict__ vhb){
  int idx = blockIdx.x*256 + threadIdx.x;
  if (idx >= BB*H_*NIN) return;
  int n  = idx & (NIN-1);
  int bh = idx >> 12;
  int h  = bh % H_;
  int b  = bh / H_;
  float T = temp[0];
  int iy = n >> 6, ix = n & 63;
  const float* src = kvbuf + ((size_t)b*NIN + n)*768 + h*HD;
  float xv[HD];
#pragma unroll
  for (int d4=0; d4<8; d4++){
    float4 v = *(const float4*)(src + d4*4);
    xv[d4*4]=v.x; xv[d4*4+1]=v.y; xv[d4*4+2]=v.z; xv[d4*4+3]=v.w;
  }
  float out[HD];
#pragma unroll
  for (int tp=0; tp<8; tp++){
    int s2 = tp >> 2, p2 = tp & 3;
    float coord = (s2==0) ? (float)iy : (float)ix;   // spacing 1.0
    float ang = coord * rf[(h*2+s2)*4 + p2];
    float sn, cn; sincosf(ang, &sn, &cn);
    float x1 = xv[2*tp], x2 = xv[2*tp+1];
    out[2*tp]   = x1*cn - x2*sn;
    out[2*tp+1] = x1*sn + x2*cn;
  }
#pragma unroll
  for (int d=16; d<HD; d++) out[d] = xv[d];
  float* dk = krose + ((size_t)bh*NIN + n)*HD;
#pragma unroll
  for (int d4=0; d4<8; d4++)
    *(float4*)(dk + d4*4) = make_float4(T*out[d4*4],T*out[d4*4+1],T*out[d4*4+2],T*out[d4*4+3]);
  const float* vs = src + D_;
  float* dv = vhb + ((size_t)bh*NIN + n)*HD;
#pragma unroll
  for (int d4=0; d4<8; d4++)
    *(float4*)(dv + d4*4) = *(const float4*)(vs + d4*4);
}

// ------------- rose for Q (grid 22x22, spacing 3.0) -------------------------
__global__ __launch_bounds__(256)
void roseq(const float* __restrict__ qp, const float* __restrict__ rf,
           float* __restrict__ qrose){
  int idx = blockIdx.x*256 + threadIdx.x;
  if (idx >= BB*H_*NOUT) return;
  int q  = idx % NOUT;
  int bh = idx / NOUT;
  int h  = bh % H_;
  int b  = bh / H_;
  int oy = q / QW_, ox = q - oy*QW_;
  const float* src = qp + ((size_t)b*NOUT + q)*D_ + h*HD;
  float xv[HD];
#pragma unroll
  for (int d4=0; d4<8; d4++){
    float4 v = *(const float4*)(src + d4*4);
    xv[d4*4]=v.x; xv[d4*4+1]=v.y; xv[d4*4+2]=v.z; xv[d4*4+3]=v.w;
  }
  float out[HD];
#pragma unroll
  for (int tp=0; tp<8; tp++){
    int s2 = tp >> 2, p2 = tp & 3;
    float coord = (s2==0) ? 3.0f*(float)oy : 3.0f*(float)ox;   // spacing 3.0
    float ang = coord * rf[(h*2+s2)*4 + p2];
    float sn, cn; sincosf(ang, &sn, &cn);
    float x1 = xv[2*tp], x2 = xv[2*tp+1];
    out[2*tp]   = x1*cn - x2*sn;
    out[2*tp+1] = x1*sn + x2*cn;
  }
#pragma unroll
  for (int d=16; d<HD; d++) out[d] = xv[d];
  float* dq = qrose + ((size_t)bh*NOUT + q)*HD;
#pragma unroll
  for (int d4=0; d4<8; d4++)
    *(float4*)(dq + d4*4) = make_float4(out[d4*4],out[d4*4+1],out[d4*4+2],out[d4*4+3]);
}

// macro: 4x4 score micro-tile over d=32 from Qs/Ks tiles
#define SCORE_LOOP(SARR, Q4, K4)                                            \
  {                                                                          \
_Pragma("unroll 8")                                                          \
    for (int d=0; d<HD; d++){                                                \
      float a0=Qs[(Q4)+0][d],a1=Qs[(Q4)+1][d],a2=Qs[(Q4)+2][d],a3=Qs[(Q4)+3][d]; \
      float b0=Ks[(K4)+0][d],b1=Ks[(K4)+1][d],b2=Ks[(K4)+2][d],b3=Ks[(K4)+3][d]; \
      SARR[0][0]+=a0*b0; SARR[0][1]+=a0*b1; SARR[0][2]+=a0*b2; SARR[0][3]+=a0*b3; \
      SARR[1][0]+=a1*b0; SARR[1][1]+=a1*b1; SARR[1][2]+=a1*b2; SARR[1][3]+=a1*b3; \
      SARR[2][0]+=a2*b0; SARR[2][1]+=a2*b1; SARR[2][2]+=a2*b2; SARR[2][3]+=a2*b3; \
      SARR[3][0]+=a3*b0; SARR[3][1]+=a3*b1; SARR[3][2]+=a3*b2; SARR[3][3]+=a3*b3; \
    }                                                                        \
  }

// ---------- S1: l0inv[bh][q] = 1/sum_k exp(s) ; q-tile 32 per block ---------
__global__ __launch_bounds__(256)
void s1k(const float* __restrict__ qr, const float* __restrict__ kr,
         float* __restrict__ l0inv){
  __shared__ float Qs[32][33];
  __shared__ float Ks[128][33];
  __shared__ float red[32][33];
  const int t = threadIdx.x;
  const int q0 = blockIdx.x*32;
  const int bh = blockIdx.y;
  {
    int q = t>>3, dq = (t&7)<<2;
    float4 v = make_float4(0.f,0.f,0.f,0.f);
    if (q0+q < NOUT) v = *(const float4*)(qr + ((size_t)bh*NOUT + q0 + q)*HD + dq);
    Qs[q][dq]=v.x; Qs[q][dq+1]=v.y; Qs[q][dq+2]=v.z; Qs[q][dq+3]=v.w;
  }
  const int g = t&7, c = t>>3;
  const int q4 = g*4, k4 = c*4;
  float rs[4] = {0.f,0.f,0.f,0.f};
  for (int kc=0; kc<NIN; kc+=128){
    __syncthreads();
    {
      int r = t>>1, dh = (t&1)<<4;
      const float* p = kr + ((size_t)bh*NIN + kc + r)*HD + dh;
      float4 v0=*(const float4*)p, v1=*(const float4*)(p+4),
             v2=*(const float4*)(p+8), v3=*(const float4*)(p+12);
      Ks[r][dh+0]=v0.x; Ks[r][dh+1]=v0.y; Ks[r][dh+2]=v0.z; Ks[r][dh+3]=v0.w;
      Ks[r][dh+4]=v1.x; Ks[r][dh+5]=v1.y; Ks[r][dh+6]=v1.z; Ks[r][dh+7]=v1.w;
      Ks[r][dh+8]=v2.x; Ks[r][dh+9]=v2.y; Ks[r][dh+10]=v2.z; Ks[r][dh+11]=v2.w;
      Ks[r][dh+12]=v3.x; Ks[r][dh+13]=v3.y; Ks[r][dh+14]=v3.z; Ks[r][dh+15]=v3.w;
    }
    __syncthreads();
    float s[4][4];
#pragma unroll
    for (int i=0;i<4;i++)
#pragma unroll
      for (int j=0;j<4;j++) s[i][j]=0.f;
    SCORE_LOOP(s, q4, k4);
#pragma unroll
    for (int i=0;i<4;i++)
      rs[i] += __expf(s[i][0])+__expf(s[i][1])+__expf(s[i][2])+__expf(s[i][3]);
  }
#pragma unroll
  for (int i=0;i<4;i++) red[q4+i][c] = rs[i];
  __syncthreads();
  if (t < 32){
    float ssum = 0.f;
#pragma unroll
    for (int cc=0; cc<32; cc++) ssum += red[t][cc];
    int q = q0 + t;
    l0inv[(size_t)bh*512 + q] = (q < NOUT) ? 1.f/ssum : 0.f;
  }
}

// ---------- S2: csinv[bh][k] = 1/(sum_q exp(s)*l0inv[q] + EPS) --------------
// k-tile 128 per block, q streamed; WK: also write attn_k (last iter)
template<bool WK>
__global__ __launch_bounds__(256)
void s2k(const float* __restrict__ qr, const float* __restrict__ kr,
         const float* __restrict__ l0inv, float* __restrict__ csinv,
         float* __restrict__ attnk){
  __shared__ float Ks[128][33];
  __shared__ float Qs[32][33];
  __shared__ float red[128][9];
  const int t = threadIdx.x;
  const int k0 = blockIdx.x*128;
  const int bh = blockIdx.y;
  {
    int r = t>>1, dh = (t&1)<<4;
    const float* p = kr + ((size_t)bh*NIN + k0 + r)*HD + dh;
    float4 v0=*(const float4*)p, v1=*(const float4*)(p+4),
           v2=*(const float4*)(p+8), v3=*(const float4*)(p+12);
    Ks[r][dh+0]=v0.x; Ks[r][dh+1]=v0.y; Ks[r][dh+2]=v0.z; Ks[r][dh+3]=v0.w;
    Ks[r][dh+4]=v1.x; Ks[r][dh+5]=v1.y; Ks[r][dh+6]=v1.z; Ks[r][dh+7]=v1.w;
    Ks[r][dh+8]=v2.x; Ks[r][dh+9]=v2.y; Ks[r][dh+10]=v2.z; Ks[r][dh+11]=v2.w;
    Ks[r][dh+12]=v3.x; Ks[r][dh+13]=v3.y; Ks[r][dh+14]=v3.z; Ks[r][dh+15]=v3.w;
  }
  const int g = t&7, c = t>>3;
  const int q4g = g*4, k4 = c*4;
  float cs[4] = {0.f,0.f,0.f,0.f};
  for (int qc=0; qc<512; qc+=32){
    __syncthreads();
    {
      int q = t>>3, dq = (t&7)<<2;
      float4 v = make_float4(0.f,0.f,0.f,0.f);
      if (qc+q < NOUT) v = *(const float4*)(qr + ((size_t)bh*NOUT + qc + q)*HD + dq);
      Qs[q][dq]=v.x; Qs[q][dq+1]=v.y; Qs[q][dq+2]=v.z; Qs[q][dq+3]=v.w;
    }
    __syncthreads();
    float li[4];
#pragma unroll
    for (int i=0;i<4;i++) li[i] = l0inv[(size_t)bh*512 + qc + q4g + i];
    float s[4][4];
#pragma unroll
    for (int i=0;i<4;i++)
#pragma unroll
      for (int j=0;j<4;j++) s[i][j]=0.f;
    SCORE_LOOP(s, q4g, k4);
    float p4[4][4];
#pragma unroll
    for (int i=0;i<4;i++)
#pragma unroll
      for (int j=0;j<4;j++) p4[i][j] = __expf(s[i][j]) * li[i];
#pragma unroll
    for (int j=0;j<4;j++) cs[j] += p4[0][j]+p4[1][j]+p4[2][j]+p4[3][j];
    if (WK){
#pragma unroll
      for (int i=0;i<4;i++){
        int q = qc + q4g + i;
        if (q < NOUT)
          *(float4*)(attnk + ((size_t)bh*NOUT + q)*NIN + k0 + k4) =
            make_float4(p4[i][0],p4[i][1],p4[i][2],p4[i][3]);
      }
    }
  }
#pragma unroll
  for (int j=0;j<4;j++) red[k4+j][g] = cs[j];
  __syncthreads();
  if (t < 128){
    float ssum = 0.f;
#pragma unroll
    for (int gg=0; gg<8; gg++) ssum += red[t][gg];
    csinv[(size_t)bh*NIN + k0 + t] = 1.f/(ssum + EPS_);
  }
}

// ---------- S3: upd[bh][q][d] = sum_k p*csinv[k]*v[k][d]; WQ writes attn_q --
template<bool WQ>
__global__ __launch_bounds__(256)
void s3k(const float* __restrict__ qr, const float* __restrict__ kr,
         const float* __restrict__ vh, const float* __restrict__ l0inv,
         const float* __restrict__ csinv, float* __restrict__ upd,
         float* __restrict__ attnq){
  __shared__ float Qs[32][33];
  __shared__ float Ks[128][33];
  __shared__ float Vs[128][33];
  __shared__ float Ps[32][132];
  const int t = threadIdx.x;
  const int q0 = blockIdx.x*32;
  const int bh = blockIdx.y;
  {
    int q = t>>3, dq = (t&7)<<2;
    float4 v = make_float4(0.f,0.f,0.f,0.f);
    if (q0+q < NOUT) v = *(const float4*)(qr + ((size_t)bh*NOUT + q0 + q)*HD + dq);
    Qs[q][dq]=v.x; Qs[q][dq+1]=v.y; Qs[q][dq+2]=v.z; Qs[q][dq+3]=v.w;
  }
  const int g = t&7, c = t>>3;
  const int q4g = g*4, k4 = c*4;
  float li[4];
#pragma unroll
  for (int i=0;i<4;i++) li[i] = l0inv[(size_t)bh*512 + q0 + q4g + i];
  const int dd = t&31, qg = t>>5;
  float acc[4] = {0.f,0.f,0.f,0.f};
  for (int kc=0; kc<NIN; kc+=128){
    __syncthreads();
    {
      int r = t>>1, dh = (t&1)<<4;
      const float* pk = kr + ((size_t)bh*NIN + kc + r)*HD + dh;
      const float* pv = vh + ((size_t)bh*NIN + kc + r)*HD + dh;
      float4 a0=*(const float4*)pk, a1=*(const float4*)(pk+4),
             a2=*(const float4*)(pk+8), a3=*(const float4*)(pk+12);
      float4 b0=*(const float4*)pv, b1=*(const float4*)(pv+4),
             b2=*(const float4*)(pv+8), b3=*(const float4*)(pv+12);
      Ks[r][dh+0]=a0.x; Ks[r][dh+1]=a0.y; Ks[r][dh+2]=a0.z; Ks[r][dh+3]=a0.w;
      Ks[r][dh+4]=a1.x; Ks[r][dh+5]=a1.y; Ks[r][dh+6]=a1.z; Ks[r][dh+7]=a1.w;
      Ks[r][dh+8]=a2.x; Ks[r][dh+9]=a2.y; Ks[r][dh+10]=a2.z; Ks[r][dh+11]=a2.w;
      Ks[r][dh+12]=a3.x; Ks[r][dh+13]=a3.y; Ks[r][dh+14]=a3.z; Ks[r][dh+15]=a3.w;
      Vs[r][dh+0]=b0.x; Vs[r][dh+1]=b0.y; Vs[r][dh+2]=b0.z; Vs[r][dh+3]=b0.w;
      Vs[r][dh+4]=b1.x; Vs[r][dh+5]=b1.y; Vs[r][dh+6]=b1.z; Vs[r][dh+7]=b1.w;
      Vs[r][dh+8]=b2.x; Vs[r][dh+9]=b2.y; Vs[r][dh+10]=b2.z; Vs[r][dh+11]=b2.w;
      Vs[r][dh+12]=b3.x; Vs[r][dh+13]=b3.y; Vs[r][dh+14]=b3.z; Vs[r][dh+15]=b3.w;
    }
    __syncthreads();
    float ci[4];
#pragma unroll
    for (int j=0;j<4;j++) ci[j] = csinv[(size_t)bh*NIN + kc + k4 + j];
    float s[4][4];
#pragma unroll
    for (int i=0;i<4;i++)
#pragma unroll
      for (int j=0;j<4;j++) s[i][j]=0.f;
    SCORE_LOOP(s, q4g, k4);
#pragma unroll
    for (int i=0;i<4;i++){
      float p0 = __expf(s[i][0])*li[i]*ci[0];
      float p1 = __expf(s[i][1])*li[i]*ci[1];
      float p2 = __expf(s[i][2])*li[i]*ci[2];
      float p3 = __expf(s[i][3])*li[i]*ci[3];
      Ps[q4g+i][k4+0]=p0; Ps[q4g+i][k4+1]=p1; Ps[q4g+i][k4+2]=p2; Ps[q4g+i][k4+3]=p3;
      if (WQ){
        int q = q0 + q4g + i;
        if (q < NOUT)
          *(float4*)(attnq + ((size_t)bh*NOUT + q)*NIN + kc + k4) = make_float4(p0,p1,p2,p3);
      }
    }
    __syncthreads();
#pragma unroll 4
    for (int kk=0; kk<128; kk+=4){
      float v0=Vs[kk][dd], v1=Vs[kk+1][dd], v2=Vs[kk+2][dd], v3=Vs[kk+3][dd];
#pragma unroll
      for (int i=0;i<4;i++){
        float4 pr = *(const float4*)&Ps[qg*4+i][kk];
        acc[i] += pr.x*v0 + pr.y*v1 + pr.z*v2 + pr.w*v3;
      }
    }
  }
#pragma unroll
  for (int i=0;i<4;i++){
    int q = q0 + qg*4 + i;
    if (q < NOUT) upd[((size_t)bh*NOUT + q)*HD + dd] = acc[i];
  }
}

__global__ __launch_bounds__(256)
void copyk(const float* __restrict__ src, float* __restrict__ dst, int n){
  int i = blockIdx.x*256 + threadIdx.x;
  if (i < n) dst[i] = src[i];
}

// --------------------------------------------------------------------------
extern "C" void kernel_launch(void* const* d_in, const int* in_sizes, int n_in,
                              void* d_out, int out_size, void* d_ws, size_t ws_size,
                              hipStream_t stream){
  (void)in_sizes; (void)n_in; (void)out_size; (void)ws_size;
  const float* px    = (const float*)d_in[0];
  const float* pcw   = (const float*)d_in[1];
  const float* pcb   = (const float*)d_in[2];
  const float* pkvw  = (const float*)d_in[3];
  const float* pkvb  = (const float*)d_in[4];
  const float* pqw   = (const float*)d_in[5];
  const float* pqb   = (const float*)d_in[6];
  const float* pw1   = (const float*)d_in[7];
  const float* pb1   = (const float*)d_in[8];
  const float* pw2   = (const float*)d_in[9];
  const float* pb2   = (const float*)d_in[10];
  const float* pg1   = (const float*)d_in[11];
  const float* pbe1  = (const float*)d_in[12];
  const float* pg2   = (const float*)d_in[13];
  const float* pbe2  = (const float*)d_in[14];
  const float* pg3   = (const float*)d_in[15];
  const float* pbe3  = (const float*)d_in[16];
  const float* ptemp = (const float*)d_in[17];
  const float* prf   = (const float*)d_in[18];

  float* out = (float*)d_out;
  float* ws  = (float*)d_ws;

  float* xout  = ws + OXOUT;
  float* krose = ws + OKROSE;
  float* vhb   = ws + OVH;
  float* qrose = ws + OQROSE;
  float* qp    = ws + OQP;
  float* l0inv = ws + OL0;
  float* csinv = ws + OCS;
  float* updb  = ws + OUPD;
  float* h1    = ws + OH1;
  float* h2    = ws + OH2;

  // d_out regions double as scratch until the last iteration writes attn
  float* attnq = out + 371712;
  float* attnk = out + 371712 + 47579136;
  float* kvbuf = attnq;             // 6.29M floats, dead before attn_q written
  float* Wt    = attnk;             // 7.23M floats, dead after conv
  float* cpart = attnq + 8388608;   // 12*371712 floats, dead after ln1

  // ---- precompute (loop-invariant) ----
  wtk<<<dim3((CK*D_+255)/256), 256, 0, stream>>>(pcw, Wt);
  convk<<<dim3(8,3,KSPLIT), 256, 0, stream>>>(px, Wt, cpart);
  lnk<0><<<dim3(MOUT), 384, 0, stream>>>(cpart, pcb, pg1, pbe1, xout);
  gemm64<0><<<dim3(128,12), 256, 0, stream>>>(px, pkvw, pkvb, kvbuf, MIN_, 768, D_);
  rosek<<<dim3((BB*H_*NIN+255)/256), 256, 0, stream>>>(kvbuf, prf, ptemp, krose, vhb);

  // ---- 3 iterations ----
  for (int it=0; it<3; ++it){
    gemm64<0><<<dim3(16,6), 256, 0, stream>>>(xout, pqw, pqb, qp, MOUT, D_, D_);
    roseq<<<dim3((BB*H_*NOUT+255)/256), 256, 0, stream>>>(qp, prf, qrose);
    s1k<<<dim3(16,24), 256, 0, stream>>>(qrose, krose, l0inv);
    if (it==2){
      s2k<true ><<<dim3(32,24), 256, 0, stream>>>(qrose, krose, l0inv, csinv, attnk);
      s3k<true ><<<dim3(16,24), 256, 0, stream>>>(qrose, krose, vhb, l0inv, csinv, updb, attnq);
    } else {
      s2k<false><<<dim3(32,24), 256, 0, stream>>>(qrose, krose, l0inv, csinv, attnk);
      s3k<false><<<dim3(16,24), 256, 0, stream>>>(qrose, krose, vhb, l0inv, csinv, updb, attnq);
    }
    lnk<1><<<dim3(MOUT), 384, 0, stream>>>(updb, pcb, pg2, pbe2, xout);
    gemm64<1><<<dim3(16,24), 256, 0, stream>>>(xout, pw1, pb1, h1, MOUT, 1536, D_);
    gemm64<0><<<dim3(16,6), 256, 0, stream>>>(h1, pw2, pb2, h2, MOUT, D_, 1536);
    lnk<2><<<dim3(MOUT), 384, 0, stream>>>(h2, pcb, pg3, pbe3, xout);
  }

  copyk<<<dim3((371712+255)/256), 256, 0, stream>>>(xout, out, 371712);
}

// Round 2
// 2149.658 us; speedup vs baseline: 1.2285x; 1.2285x over previous
//
#include <hip/hip_runtime.h>
#include <math.h>

// ---------------- problem constants ----------------
#define BB 2
#define D_ 384
#define H_ 12
#define HD 32
#define NIN 4096            // 64*64
#define NOUT 484            // 22*22
#define MOUT (BB*NOUT)      // 968
#define MIN_ (BB*NIN)       // 8192
#define QW_ 22
#define CK 18816            // D*7*7
#define NSLICE 49           // conv split-K: one slice per (ky,kx), K=384 each
#define LN_EPS 1e-5f
#define EPS_ 1.1920929e-07f

typedef short bf16x8 __attribute__((ext_vector_type(8)));
typedef float f32x4  __attribute__((ext_vector_type(4)));

__device__ __forceinline__ unsigned f2bf(float f){   // RNE fp32->bf16 bits
  unsigned u = __float_as_uint(f);
  u += 0x7fffu + ((u>>16)&1u);
  return u>>16;
}

// ---------------- ws layout (floats) ----------------
static const size_t OXOUT  = 0;                    // 968*384      = 371712
static const size_t OKROSE = 371712;               // 24*4096*32   = 3145728
static const size_t OVH    = OKROSE + 3145728;
static const size_t OQROSE = OVH + 3145728;        // 371712
static const size_t OQP    = OQROSE + 371712;      // 371712
static const size_t OL0    = OQP + 371712;         // 12288
static const size_t OCS    = OL0 + 12288;          // 98304
static const size_t OUPD   = OCS + 98304;          // 371712
static const size_t OH1    = OUPD + 371712;        // 1486848
static const size_t OH2    = OH1 + 1486848;        // 371712
static const size_t OQWB   = OH2 + 371712;         // 384*384 bf16   = 73728 f
static const size_t OW1B   = OQWB + 73728;         // 384*1536 bf16  = 294912 f
static const size_t OW2B   = OW1B + 294912;        // 1536*384 bf16  = 294912 f
// total = 10,411,008 floats = 41.6 MB

// ---------------- packing kernels ----------------
__global__ __launch_bounds__(256)
void packxk(const float* __restrict__ x, ushort* __restrict__ xb){
  int i = blockIdx.x*256 + threadIdx.x;           // one float4 per thread
  int base = i*4;
  if (base >= MIN_*D_) return;
  float4 v = *(const float4*)(x + base);
  uint2 o;
  o.x = f2bf(v.x) | (f2bf(v.y)<<16);
  o.y = f2bf(v.z) | (f2bf(v.w)<<16);
  *(uint2*)(xb + base) = o;
}

// conv_w [n][di][ky][kx] -> Wtb[kyx][n][di] (bf16)
__global__ __launch_bounds__(256)
void wtk2(const float* __restrict__ cw, ushort* __restrict__ wtb){
  int i = blockIdx.x*256 + threadIdx.x;
  if (i >= CK*D_) return;
  int n = i / CK;
  int r = i - n*CK;           // di*49 + kyx
  int di = r/49, kyx = r - di*49;
  wtb[((size_t)kyx*D_ + n)*D_ + di] = (ushort)f2bf(cw[i]);
}

// w[k][n] fp32 -> wb[n][k] bf16
__global__ __launch_bounds__(256)
void packwk(const float* __restrict__ w, ushort* __restrict__ wb, int K, int N){
  int i = blockIdx.x*256 + threadIdx.x;
  if (i >= K*N) return;
  int k = i / N, n = i - k*N;
  wb[(size_t)n*K + k] = (ushort)f2bf(w[i]);
}

// -------- MFMA conv: per-slice GEMM, 128x128 tile, 4 waves x (4x4) 16x16x32 --------
__global__ __launch_bounds__(256)
void convm(const ushort* __restrict__ xb, const ushort* __restrict__ wtb,
           float* __restrict__ part){
  __shared__ ushort As[128][40];     // [m][k], +8 pad -> 2-way-only conflicts
  __shared__ ushort Bs[128][40];     // [n][k]  (W^T)
  const int t  = threadIdx.x;
  const int m0 = blockIdx.x*128, n0 = blockIdx.y*128, z = blockIdx.z;
  const int ky = z/7, kx = z - ky*7;
  const int r = t>>1, half = t&1;
  const int m = m0 + r;
  const int mq = (m < MOUT) ? m : 0;
  const int bbv = mq/NOUT, qq = mq - bbv*NOUT;
  const int oy = qq/QW_, ox = qq - oy*QW_;
  const int iy = oy*3-3+ky, ix = ox*3-3+kx;
  const bool aval = (m<MOUT) && iy>=0 && iy<64 && ix>=0 && ix<64;
  const ushort* asrc = xb + ((size_t)bbv*NIN + (aval ? iy*64+ix : 0))*D_ + half*16;
  const ushort* bsrc = wtb + ((size_t)z*D_ + n0 + r)*D_ + half*16;

  const int wv = t>>6;
  const int wr = (wv>>1)*64, wc = (wv&1)*64;
  const int ln = t&15, lq = (t>>4)&3;

  f32x4 acc[4][4];
#pragma unroll
  for (int i=0;i<4;i++)
#pragma unroll
    for (int j=0;j<4;j++) acc[i][j] = (f32x4){0.f,0.f,0.f,0.f};

  for (int dk=0; dk<D_; dk+=32){
    uint4 a0 = {0,0,0,0}, a1 = {0,0,0,0};
    if (aval){ a0 = *(const uint4*)(asrc+dk); a1 = *(const uint4*)(asrc+dk+8); }
    uint4 b0 = *(const uint4*)(bsrc+dk), b1 = *(const uint4*)(bsrc+dk+8);
    *(uint4*)&As[r][half*16]   = a0;  *(uint4*)&As[r][half*16+8] = a1;
    *(uint4*)&Bs[r][half*16]   = b0;  *(uint4*)&Bs[r][half*16+8] = b1;
    __syncthreads();
    bf16x8 af[4], bfr[4];
#pragma unroll
    for (int i=0;i<4;i++) af[i]  = *(const bf16x8*)&As[wr+i*16+ln][lq*8];
#pragma unroll
    for (int j=0;j<4;j++) bfr[j] = *(const bf16x8*)&Bs[wc+j*16+ln][lq*8];
#pragma unroll
    for (int i=0;i<4;i++)
#pragma unroll
      for (int j=0;j<4;j++)
        acc[i][j] = __builtin_amdgcn_mfma_f32_16x16x32_bf16(af[i], bfr[j], acc[i][j], 0,0,0);
    __syncthreads();
  }
#pragma unroll
  for (int i=0;i<4;i++){
    int rowb = m0 + wr + i*16 + lq*4;
#pragma unroll
    for (int j=0;j<4;j++){
      int col = n0 + wc + j*16 + ln;
#pragma unroll
      for (int rg=0; rg<4; rg++){
        int row = rowb + rg;
        if (row < MOUT) part[((size_t)z*MOUT + row)*D_ + col] = acc[i][j][rg];
      }
    }
  }
}

// -------- MFMA GEMM: C = A[M,K]*W[K,N] + bias, W pre-packed as Wb[n][k] bf16 -----
// ACT: 0 none, 1 exact gelu. ABF: A already bf16 (else fp32, converted on stage).
template<int ACT, bool ABF>
__global__ __launch_bounds__(256)
void gemmm(const void* __restrict__ Ain, const ushort* __restrict__ Wb,
           const float* __restrict__ bias, float* __restrict__ C,
           int M, int N, int K){
  __shared__ ushort As[128][40];
  __shared__ ushort Bs[128][40];
  const int t  = threadIdx.x;
  const int m0 = blockIdx.x*128, n0 = blockIdx.y*128;
  const int r = t>>1, half = t&1;
  const int m = m0 + r;
  const bool aval = (m < M);
  const float*  af32 = (const float*)Ain  + (size_t)(aval?m:0)*K + half*16;
  const ushort* ab16 = (const ushort*)Ain + (size_t)(aval?m:0)*K + half*16;
  const ushort* bsrc = Wb + (size_t)(n0 + r)*K + half*16;

  const int wv = t>>6;
  const int wr = (wv>>1)*64, wc = (wv&1)*64;
  const int ln = t&15, lq = (t>>4)&3;

  f32x4 acc[4][4];
#pragma unroll
  for (int i=0;i<4;i++)
#pragma unroll
    for (int j=0;j<4;j++) acc[i][j] = (f32x4){0.f,0.f,0.f,0.f};

  for (int dk=0; dk<K; dk+=32){
    uint4 a0 = {0,0,0,0}, a1 = {0,0,0,0};
    if (aval){
      if (ABF){
        a0 = *(const uint4*)(ab16+dk); a1 = *(const uint4*)(ab16+dk+8);
      } else {
        float4 f0 = *(const float4*)(af32+dk),   f1 = *(const float4*)(af32+dk+4);
        float4 f2 = *(const float4*)(af32+dk+8), f3 = *(const float4*)(af32+dk+12);
        a0.x = f2bf(f0.x)|(f2bf(f0.y)<<16); a0.y = f2bf(f0.z)|(f2bf(f0.w)<<16);
        a0.z = f2bf(f1.x)|(f2bf(f1.y)<<16); a0.w = f2bf(f1.z)|(f2bf(f1.w)<<16);
        a1.x = f2bf(f2.x)|(f2bf(f2.y)<<16); a1.y = f2bf(f2.z)|(f2bf(f2.w)<<16);
        a1.z = f2bf(f3.x)|(f2bf(f3.y)<<16); a1.w = f2bf(f3.z)|(f2bf(f3.w)<<16);
      }
    }
    uint4 b0 = *(const uint4*)(bsrc+dk), b1 = *(const uint4*)(bsrc+dk+8);
    *(uint4*)&As[r][half*16]   = a0;  *(uint4*)&As[r][half*16+8] = a1;
    *(uint4*)&Bs[r][half*16]   = b0;  *(uint4*)&Bs[r][half*16+8] = b1;
    __syncthreads();
    bf16x8 af[4], bfr[4];
#pragma unroll
    for (int i=0;i<4;i++) af[i]  = *(const bf16x8*)&As[wr+i*16+ln][lq*8];
#pragma unroll
    for (int j=0;j<4;j++) bfr[j] = *(const bf16x8*)&Bs[wc+j*16+ln][lq*8];
#pragma unroll
    for (int i=0;i<4;i++)
#pragma unroll
      for (int j=0;j<4;j++)
        acc[i][j] = __builtin_amdgcn_mfma_f32_16x16x32_bf16(af[i], bfr[j], acc[i][j], 0,0,0);
    __syncthreads();
  }
#pragma unroll
  for (int i=0;i<4;i++){
    int rowb = m0 + wr + i*16 + lq*4;
#pragma unroll
    for (int j=0;j<4;j++){
      int col = n0 + wc + j*16 + ln;
      float bv = bias[col];
#pragma unroll
      for (int rg=0; rg<4; rg++){
        int row = rowb + rg;
        if (row < M){
          float v = acc[i][j][rg] + bv;
          if (ACT==1) v = 0.5f*v*(1.f + erff(v*0.7071067811865475f));
          C[(size_t)row*N + col] = v;
        }
      }
    }
  }
}

// ---------------- block reduction over 384 threads --------------------------
__device__ __forceinline__ float block_sum_384(float v){
  __shared__ float red[6];
#pragma unroll
  for (int o=32;o>0;o>>=1) v += __shfl_down(v,o);
  const int lane = threadIdx.x & 63, w = threadIdx.x >> 6;
  __syncthreads();
  if (lane==0) red[w] = v;
  __syncthreads();
  return red[0]+red[1]+red[2]+red[3]+red[4]+red[5];
}

// LN kernel. MODE 0: in = 49 conv partials (+conv bias) -> write xout
//            MODE 1: in = upd[bh][q][hd] gathered -> xout += LN
//            MODE 2: in = h2[m][d] -> xout += LN
template<int MODE>
__global__ __launch_bounds__(384)
void lnk(const float* __restrict__ in, const float* __restrict__ cb,
         const float* __restrict__ gg, const float* __restrict__ bb,
         float* __restrict__ xout){
  const int m = blockIdx.x, d = threadIdx.x;
  float v;
  if (MODE==0){
    v = cb[d];
    for (int z=0; z<NSLICE; z++) v += in[((size_t)z*MOUT + m)*D_ + d];
  } else if (MODE==1){
    int b = m/NOUT, q = m - b*NOUT;
    int h = d>>5, dd2 = d&31;
    v = in[(((size_t)(b*H_ + h))*NOUT + q)*HD + dd2];
  } else {
    v = in[(size_t)m*D_ + d];
  }
  float mu  = block_sum_384(v) * (1.f/D_);
  float ce  = v - mu;
  float var = block_sum_384(ce*ce) * (1.f/D_);
  float o = ce * rsqrtf(var + LN_EPS) * gg[d] + bb[d];
  float* dst = xout + (size_t)m*D_ + d;
  if (MODE==0) *dst = o;
  else *dst += o;
}

// ------------- rose for K (+ temp scale) and V gather -----------------------
__global__ __launch_bounds__(256)
void rosek(const float* __restrict__ kvbuf, const float* __restrict__ rf,
           const float* __restrict__ temp,
           float* __restrict__ krose, float* __restrict__ vhb){
  int idx = blockIdx.x*256 + threadIdx.x;
  if (idx >= BB*H_*NIN) return;
  int n  = idx & (NIN-1);
  int bh = idx >> 12;
  int h  = bh % H_;
  int b  = bh / H_;
  float T = temp[0];
  int iy = n >> 6, ix = n & 63;
  const float* src = kvbuf + ((size_t)b*NIN + n)*768 + h*HD;
  float xv[HD];
#pragma unroll
  for (int d4=0; d4<8; d4++){
    float4 v = *(const float4*)(src + d4*4);
    xv[d4*4]=v.x; xv[d4*4+1]=v.y; xv[d4*4+2]=v.z; xv[d4*4+3]=v.w;
  }
  float out[HD];
#pragma unroll
  for (int tp=0; tp<8; tp++){
    int s2 = tp >> 2, p2 = tp & 3;
    float coord = (s2==0) ? (float)iy : (float)ix;
    float ang = coord * rf[(h*2+s2)*4 + p2];
    float sn, cn; sincosf(ang, &sn, &cn);
    float x1 = xv[2*tp], x2 = xv[2*tp+1];
    out[2*tp]   = x1*cn - x2*sn;
    out[2*tp+1] = x1*sn + x2*cn;
  }
#pragma unroll
  for (int d=16; d<HD; d++) out[d] = xv[d];
  float* dk = krose + ((size_t)bh*NIN + n)*HD;
#pragma unroll
  for (int d4=0; d4<8; d4++)
    *(float4*)(dk + d4*4) = make_float4(T*out[d4*4],T*out[d4*4+1],T*out[d4*4+2],T*out[d4*4+3]);
  const float* vs = src + D_;
  float* dv = vhb + ((size_t)bh*NIN + n)*HD;
#pragma unroll
  for (int d4=0; d4<8; d4++)
    *(float4*)(dv + d4*4) = *(const float4*)(vs + d4*4);
}

// ------------- rose for Q (grid 22x22, spacing 3.0) -------------------------
__global__ __launch_bounds__(256)
void roseq(const float* __restrict__ qp, const float* __restrict__ rf,
           float* __restrict__ qrose){
  int idx = blockIdx.x*256 + threadIdx.x;
  if (idx >= BB*H_*NOUT) return;
  int q  = idx % NOUT;
  int bh = idx / NOUT;
  int h  = bh % H_;
  int b  = bh / H_;
  int oy = q / QW_, ox = q - oy*QW_;
  const float* src = qp + ((size_t)b*NOUT + q)*D_ + h*HD;
  float xv[HD];
#pragma unroll
  for (int d4=0; d4<8; d4++){
    float4 v = *(const float4*)(src + d4*4);
    xv[d4*4]=v.x; xv[d4*4+1]=v.y; xv[d4*4+2]=v.z; xv[d4*4+3]=v.w;
  }
  float out[HD];
#pragma unroll
  for (int tp=0; tp<8; tp++){
    int s2 = tp >> 2, p2 = tp & 3;
    float coord = (s2==0) ? 3.0f*(float)oy : 3.0f*(float)ox;
    float ang = coord * rf[(h*2+s2)*4 + p2];
    float sn, cn; sincosf(ang, &sn, &cn);
    float x1 = xv[2*tp], x2 = xv[2*tp+1];
    out[2*tp]   = x1*cn - x2*sn;
    out[2*tp+1] = x1*sn + x2*cn;
  }
#pragma unroll
  for (int d=16; d<HD; d++) out[d] = xv[d];
  float* dq = qrose + ((size_t)bh*NOUT + q)*HD;
#pragma unroll
  for (int d4=0; d4<8; d4++)
    *(float4*)(dq + d4*4) = make_float4(out[d4*4],out[d4*4+1],out[d4*4+2],out[d4*4+3]);
}

// macro: 4x4 score micro-tile over d=32 from Qs/Ks tiles
#define SCORE_LOOP(SARR, Q4, K4)                                            \
  {                                                                          \
_Pragma("unroll 8")                                                          \
    for (int d=0; d<HD; d++){                                                \
      float a0=Qs[(Q4)+0][d],a1=Qs[(Q4)+1][d],a2=Qs[(Q4)+2][d],a3=Qs[(Q4)+3][d]; \
      float b0=Ks[(K4)+0][d],b1=Ks[(K4)+1][d],b2=Ks[(K4)+2][d],b3=Ks[(K4)+3][d]; \
      SARR[0][0]+=a0*b0; SARR[0][1]+=a0*b1; SARR[0][2]+=a0*b2; SARR[0][3]+=a0*b3; \
      SARR[1][0]+=a1*b0; SARR[1][1]+=a1*b1; SARR[1][2]+=a1*b2; SARR[1][3]+=a1*b3; \
      SARR[2][0]+=a2*b0; SARR[2][1]+=a2*b1; SARR[2][2]+=a2*b2; SARR[2][3]+=a2*b3; \
      SARR[3][0]+=a3*b0; SARR[3][1]+=a3*b1; SARR[3][2]+=a3*b2; SARR[3][3]+=a3*b3; \
    }                                                                        \
  }

// ---------- S1: l0inv[bh][q] = 1/sum_k exp(s) ---------
__global__ __launch_bounds__(256)
void s1k(const float* __restrict__ qr, const float* __restrict__ kr,
         float* __restrict__ l0inv){
  __shared__ float Qs[32][33];
  __shared__ float Ks[128][33];
  __shared__ float red[32][33];
  const int t = threadIdx.x;
  const int q0 = blockIdx.x*32;
  const int bh = blockIdx.y;
  {
    int q = t>>3, dq = (t&7)<<2;
    float4 v = make_float4(0.f,0.f,0.f,0.f);
    if (q0+q < NOUT) v = *(const float4*)(qr + ((size_t)bh*NOUT + q0 + q)*HD + dq);
    Qs[q][dq]=v.x; Qs[q][dq+1]=v.y; Qs[q][dq+2]=v.z; Qs[q][dq+3]=v.w;
  }
  const int g = t&7, c = t>>3;
  const int q4 = g*4, k4 = c*4;
  float rs[4] = {0.f,0.f,0.f,0.f};
  for (int kc=0; kc<NIN; kc+=128){
    __syncthreads();
    {
      int r = t>>1, dh = (t&1)<<4;
      const float* p = kr + ((size_t)bh*NIN + kc + r)*HD + dh;
      float4 v0=*(const float4*)p, v1=*(const float4*)(p+4),
             v2=*(const float4*)(p+8), v3=*(const float4*)(p+12);
      Ks[r][dh+0]=v0.x; Ks[r][dh+1]=v0.y; Ks[r][dh+2]=v0.z; Ks[r][dh+3]=v0.w;
      Ks[r][dh+4]=v1.x; Ks[r][dh+5]=v1.y; Ks[r][dh+6]=v1.z; Ks[r][dh+7]=v1.w;
      Ks[r][dh+8]=v2.x; Ks[r][dh+9]=v2.y; Ks[r][dh+10]=v2.z; Ks[r][dh+11]=v2.w;
      Ks[r][dh+12]=v3.x; Ks[r][dh+13]=v3.y; Ks[r][dh+14]=v3.z; Ks[r][dh+15]=v3.w;
    }
    __syncthreads();
    float s[4][4];
#pragma unroll
    for (int i=0;i<4;i++)
#pragma unroll
      for (int j=0;j<4;j++) s[i][j]=0.f;
    SCORE_LOOP(s, q4, k4);
#pragma unroll
    for (int i=0;i<4;i++)
      rs[i] += __expf(s[i][0])+__expf(s[i][1])+__expf(s[i][2])+__expf(s[i][3]);
  }
#pragma unroll
  for (int i=0;i<4;i++) red[q4+i][c] = rs[i];
  __syncthreads();
  if (t < 32){
    float ssum = 0.f;
#pragma unroll
    for (int cc=0; cc<32; cc++) ssum += red[t][cc];
    int q = q0 + t;
    l0inv[(size_t)bh*512 + q] = (q < NOUT) ? 1.f/ssum : 0.f;
  }
}

// ---------- S2: csinv[bh][k] = 1/(sum_q exp(s)*l0inv[q] + EPS) --------------
template<bool WK>
__global__ __launch_bounds__(256)
void s2k(const float* __restrict__ qr, const float* __restrict__ kr,
         const float* __restrict__ l0inv, float* __restrict__ csinv,
         float* __restrict__ attnk){
  __shared__ float Ks[128][33];
  __shared__ float Qs[32][33];
  __shared__ float red[128][9];
  const int t = threadIdx.x;
  const int k0 = blockIdx.x*128;
  const int bh = blockIdx.y;
  {
    int r = t>>1, dh = (t&1)<<4;
    const float* p = kr + ((size_t)bh*NIN + k0 + r)*HD + dh;
    float4 v0=*(const float4*)p, v1=*(const float4*)(p+4),
           v2=*(const float4*)(p+8), v3=*(const float4*)(p+12);
    Ks[r][dh+0]=v0.x; Ks[r][dh+1]=v0.y; Ks[r][dh+2]=v0.z; Ks[r][dh+3]=v0.w;
    Ks[r][dh+4]=v1.x; Ks[r][dh+5]=v1.y; Ks[r][dh+6]=v1.z; Ks[r][dh+7]=v1.w;
    Ks[r][dh+8]=v2.x; Ks[r][dh+9]=v2.y; Ks[r][dh+10]=v2.z; Ks[r][dh+11]=v2.w;
    Ks[r][dh+12]=v3.x; Ks[r][dh+13]=v3.y; Ks[r][dh+14]=v3.z; Ks[r][dh+15]=v3.w;
  }
  const int g = t&7, c = t>>3;
  const int q4g = g*4, k4 = c*4;
  float cs[4] = {0.f,0.f,0.f,0.f};
  for (int qc=0; qc<512; qc+=32){
    __syncthreads();
    {
      int q = t>>3, dq = (t&7)<<2;
      float4 v = make_float4(0.f,0.f,0.f,0.f);
      if (qc+q < NOUT) v = *(const float4*)(qr + ((size_t)bh*NOUT + qc + q)*HD + dq);
      Qs[q][dq]=v.x; Qs[q][dq+1]=v.y; Qs[q][dq+2]=v.z; Qs[q][dq+3]=v.w;
    }
    __syncthreads();
    float li[4];
#pragma unroll
    for (int i=0;i<4;i++) li[i] = l0inv[(size_t)bh*512 + qc + q4g + i];
    float s[4][4];
#pragma unroll
    for (int i=0;i<4;i++)
#pragma unroll
      for (int j=0;j<4;j++) s[i][j]=0.f;
    SCORE_LOOP(s, q4g, k4);
    float p4[4][4];
#pragma unroll
    for (int i=0;i<4;i++)
#pragma unroll
      for (int j=0;j<4;j++) p4[i][j] = __expf(s[i][j]) * li[i];
#pragma unroll
    for (int j=0;j<4;j++) cs[j] += p4[0][j]+p4[1][j]+p4[2][j]+p4[3][j];
    if (WK){
#pragma unroll
      for (int i=0;i<4;i++){
        int q = qc + q4g + i;
        if (q < NOUT)
          *(float4*)(attnk + ((size_t)bh*NOUT + q)*NIN + k0 + k4) =
            make_float4(p4[i][0],p4[i][1],p4[i][2],p4[i][3]);
      }
    }
  }
#pragma unroll
  for (int j=0;j<4;j++) red[k4+j][g] = cs[j];
  __syncthreads();
  if (t < 128){
    float ssum = 0.f;
#pragma unroll
    for (int gg=0; gg<8; gg++) ssum += red[t][gg];
    csinv[(size_t)bh*NIN + k0 + t] = 1.f/(ssum + EPS_);
  }
}

// ---------- S3: upd[bh][q][d] = sum_k p*csinv[k]*v[k][d] --------------------
template<bool WQ>
__global__ __launch_bounds__(256)
void s3k(const float* __restrict__ qr, const float* __restrict__ kr,
         const float* __restrict__ vh, const float* __restrict__ l0inv,
         const float* __restrict__ csinv, float* __restrict__ upd,
         float* __restrict__ attnq){
  __shared__ float Qs[32][33];
  __shared__ float Ks[128][33];
  __shared__ float Vs[128][33];
  __shared__ float Ps[32][132];
  const int t = threadIdx.x;
  const int q0 = blockIdx.x*32;
  const int bh = blockIdx.y;
  {
    int q = t>>3, dq = (t&7)<<2;
    float4 v = make_float4(0.f,0.f,0.f,0.f);
    if (q0+q < NOUT) v = *(const float4*)(qr + ((size_t)bh*NOUT + q0 + q)*HD + dq);
    Qs[q][dq]=v.x; Qs[q][dq+1]=v.y; Qs[q][dq+2]=v.z; Qs[q][dq+3]=v.w;
  }
  const int g = t&7, c = t>>3;
  const int q4g = g*4, k4 = c*4;
  float li[4];
#pragma unroll
  for (int i=0;i<4;i++) li[i] = l0inv[(size_t)bh*512 + q0 + q4g + i];
  const int dd = t&31, qg = t>>5;
  float acc[4] = {0.f,0.f,0.f,0.f};
  for (int kc=0; kc<NIN; kc+=128){
    __syncthreads();
    {
      int r = t>>1, dh = (t&1)<<4;
      const float* pk = kr + ((size_t)bh*NIN + kc + r)*HD + dh;
      const float* pv = vh + ((size_t)bh*NIN + kc + r)*HD + dh;
      float4 a0=*(const float4*)pk, a1=*(const float4*)(pk+4),
             a2=*(const float4*)(pk+8), a3=*(const float4*)(pk+12);
      float4 b0=*(const float4*)pv, b1=*(const float4*)(pv+4),
             b2=*(const float4*)(pv+8), b3=*(const float4*)(pv+12);
      Ks[r][dh+0]=a0.x; Ks[r][dh+1]=a0.y; Ks[r][dh+2]=a0.z; Ks[r][dh+3]=a0.w;
      Ks[r][dh+4]=a1.x; Ks[r][dh+5]=a1.y; Ks[r][dh+6]=a1.z; Ks[r][dh+7]=a1.w;
      Ks[r][dh+8]=a2.x; Ks[r][dh+9]=a2.y; Ks[r][dh+10]=a2.z; Ks[r][dh+11]=a2.w;
      Ks[r][dh+12]=a3.x; Ks[r][dh+13]=a3.y; Ks[r][dh+14]=a3.z; Ks[r][dh+15]=a3.w;
      Vs[r][dh+0]=b0.x; Vs[r][dh+1]=b0.y; Vs[r][dh+2]=b0.z; Vs[r][dh+3]=b0.w;
      Vs[r][dh+4]=b1.x; Vs[r][dh+5]=b1.y; Vs[r][dh+6]=b1.z; Vs[r][dh+7]=b1.w;
      Vs[r][dh+8]=b2.x; Vs[r][dh+9]=b2.y; Vs[r][dh+10]=b2.z; Vs[r][dh+11]=b2.w;
      Vs[r][dh+12]=b3.x; Vs[r][dh+13]=b3.y; Vs[r][dh+14]=b3.z; Vs[r][dh+15]=b3.w;
    }
    __syncthreads();
    float ci[4];
#pragma unroll
    for (int j=0;j<4;j++) ci[j] = csinv[(size_t)bh*NIN + kc + k4 + j];
    float s[4][4];
#pragma unroll
    for (int i=0;i<4;i++)
#pragma unroll
      for (int j=0;j<4;j++) s[i][j]=0.f;
    SCORE_LOOP(s, q4g, k4);
#pragma unroll
    for (int i=0;i<4;i++){
      float p0 = __expf(s[i][0])*li[i]*ci[0];
      float p1 = __expf(s[i][1])*li[i]*ci[1];
      float p2 = __expf(s[i][2])*li[i]*ci[2];
      float p3 = __expf(s[i][3])*li[i]*ci[3];
      Ps[q4g+i][k4+0]=p0; Ps[q4g+i][k4+1]=p1; Ps[q4g+i][k4+2]=p2; Ps[q4g+i][k4+3]=p3;
      if (WQ){
        int q = q0 + q4g + i;
        if (q < NOUT)
          *(float4*)(attnq + ((size_t)bh*NOUT + q)*NIN + kc + k4) = make_float4(p0,p1,p2,p3);
      }
    }
    __syncthreads();
#pragma unroll 4
    for (int kk=0; kk<128; kk+=4){
      float v0=Vs[kk][dd], v1=Vs[kk+1][dd], v2=Vs[kk+2][dd], v3=Vs[kk+3][dd];
#pragma unroll
      for (int i=0;i<4;i++){
        float4 pr = *(const float4*)&Ps[qg*4+i][kk];
        acc[i] += pr.x*v0 + pr.y*v1 + pr.z*v2 + pr.w*v3;
      }
    }
  }
#pragma unroll
  for (int i=0;i<4;i++){
    int q = q0 + qg*4 + i;
    if (q < NOUT) upd[((size_t)bh*NOUT + q)*HD + dd] = acc[i];
  }
}

__global__ __launch_bounds__(256)
void copyk(const float* __restrict__ src, float* __restrict__ dst, int n){
  int i = blockIdx.x*256 + threadIdx.x;
  if (i < n) dst[i] = src[i];
}

// --------------------------------------------------------------------------
extern "C" void kernel_launch(void* const* d_in, const int* in_sizes, int n_in,
                              void* d_out, int out_size, void* d_ws, size_t ws_size,
                              hipStream_t stream){
  (void)in_sizes; (void)n_in; (void)out_size; (void)ws_size;
  const float* px    = (const float*)d_in[0];
  const float* pcw   = (const float*)d_in[1];
  const float* pcb   = (const float*)d_in[2];
  const float* pkvw  = (const float*)d_in[3];
  const float* pkvb  = (const float*)d_in[4];
  const float* pqw   = (const float*)d_in[5];
  const float* pqb   = (const float*)d_in[6];
  const float* pw1   = (const float*)d_in[7];
  const float* pb1   = (const float*)d_in[8];
  const float* pw2   = (const float*)d_in[9];
  const float* pb2   = (const float*)d_in[10];
  const float* pg1   = (const float*)d_in[11];
  const float* pbe1  = (const float*)d_in[12];
  const float* pg2   = (const float*)d_in[13];
  const float* pbe2  = (const float*)d_in[14];
  const float* pg3   = (const float*)d_in[15];
  const float* pbe3  = (const float*)d_in[16];
  const float* ptemp = (const float*)d_in[17];
  const float* prf   = (const float*)d_in[18];

  float* out = (float*)d_out;
  float* ws  = (float*)d_ws;

  float* xout  = ws + OXOUT;
  float* krose = ws + OKROSE;
  float* vhb   = ws + OVH;
  float* qrose = ws + OQROSE;
  float* qp    = ws + OQP;
  float* l0inv = ws + OL0;
  float* csinv = ws + OCS;
  float* updb  = ws + OUPD;
  float* h1    = ws + OH1;
  float* h2    = ws + OH2;
  ushort* qwb  = (ushort*)(ws + OQWB);
  ushort* w1b  = (ushort*)(ws + OW1B);
  ushort* w2b  = (ushort*)(ws + OW2B);

  // d_out regions double as scratch until the last iteration writes attn
  float* attnq = out + 371712;
  float* attnk = out + 371712 + 47579136;
  float* kvbuf = attnq;                         // 6.29M f, dead before attn_q written
  float* cpart = attnq + 8388608;               // 49*968*384 f, dead after ln1
  ushort* wtb  = (ushort*)attnk;                // 7.23M bf16, dead after conv
  ushort* xb16 = (ushort*)(attnk + 3612672);    // 3.15M bf16, dead after rosek
  ushort* kvwb = (ushort*)(attnk + 3612672 + 1572864);  // 294912 bf16

  // ---- packing (loop-invariant) ----
  packxk<<<dim3((MIN_*D_/4 + 255)/256), 256, 0, stream>>>(px, xb16);
  wtk2  <<<dim3((CK*D_ + 255)/256), 256, 0, stream>>>(pcw, wtb);
  packwk<<<dim3((384*768 + 255)/256), 256, 0, stream>>>(pkvw, kvwb, 384, 768);
  packwk<<<dim3((384*384 + 255)/256), 256, 0, stream>>>(pqw,  qwb,  384, 384);
  packwk<<<dim3((384*1536 + 255)/256), 256, 0, stream>>>(pw1, w1b, 384, 1536);
  packwk<<<dim3((1536*384 + 255)/256), 256, 0, stream>>>(pw2, w2b, 1536, 384);

  // ---- precompute (loop-invariant) ----
  convm<<<dim3(8,3,NSLICE), 256, 0, stream>>>(xb16, wtb, cpart);
  lnk<0><<<dim3(MOUT), 384, 0, stream>>>(cpart, pcb, pg1, pbe1, xout);
  gemmm<0,true><<<dim3(64,6), 256, 0, stream>>>(xb16, kvwb, pkvb, kvbuf, MIN_, 768, 384);
  rosek<<<dim3((BB*H_*NIN+255)/256), 256, 0, stream>>>(kvbuf, prf, ptemp, krose, vhb);

  // ---- 3 iterations ----
  for (int it=0; it<3; ++it){
    gemmm<0,false><<<dim3(8,3), 256, 0, stream>>>(xout, qwb, pqb, qp, MOUT, 384, 384);
    roseq<<<dim3((BB*H_*NOUT+255)/256), 256, 0, stream>>>(qp, prf, qrose);
    s1k<<<dim3(16,24), 256, 0, stream>>>(qrose, krose, l0inv);
    if (it==2){
      s2k<true ><<<dim3(32,24), 256, 0, stream>>>(qrose, krose, l0inv, csinv, attnk);
      s3k<true ><<<dim3(16,24), 256, 0, stream>>>(qrose, krose, vhb, l0inv, csinv, updb, attnq);
    } else {
      s2k<false><<<dim3(32,24), 256, 0, stream>>>(qrose, krose, l0inv, csinv, attnk);
      s3k<false><<<dim3(16,24), 256, 0, stream>>>(qrose, krose, vhb, l0inv, csinv, updb, attnq);
    }
    lnk<1><<<dim3(MOUT), 384, 0, stream>>>(updb, pcb, pg2, pbe2, xout);
    gemmm<1,false><<<dim3(8,12), 256, 0, stream>>>(xout, w1b, pb1, h1, MOUT, 1536, 384);
    gemmm<0,false><<<dim3(8,3), 256, 0, stream>>>(h1, w2b, pb2, h2, MOUT, 384, 1536);
    lnk<2><<<dim3(MOUT), 384, 0, stream>>>(h2, pcb, pg3, pbe3, xout);
  }

  copyk<<<dim3((371712+255)/256), 256, 0, stream>>>(xout, out, 371712);
}